// Round 10
// baseline (476.618 us; speedup 1.0000x reference)
//
#include <hip/hip_runtime.h>

#define NV 100000
#define NC 50000
#define DVAR 8
#define DCON 16

using short8 = __attribute__((ext_vector_type(8))) short;
using f32x4  = __attribute__((ext_vector_type(4))) float;

typedef const __attribute__((address_space(1))) void* as1cv;
typedef __attribute__((address_space(3))) void* as3v;

__device__ __forceinline__ unsigned short f2bf(float f) {
    union { float f; unsigned int u; } v; v.f = f;
    return (unsigned short)((v.u + 0x7fffu + ((v.u >> 16) & 1u)) >> 16);  // RNE
}
__device__ __forceinline__ float bflo(unsigned int u) {
    union { unsigned int u; float f; } v; v.u = u << 16; return v.f;
}
__device__ __forceinline__ float bfhi(unsigned int u) {
    union { unsigned int u; float f; } v; v.u = u & 0xffff0000u; return v.f;
}

// ---------------------------------------------------------------- pack W into MFMA B-fragment
__global__ __launch_bounds__(256) void pack_kernel(
    const float* __restrict__ Wvar, const float* __restrict__ Wcon,
    const float* __restrict__ Wiv,  const float* __restrict__ Wic,
    unsigned short* __restrict__ WbVar, unsigned short* __restrict__ WbCon,
    unsigned short* __restrict__ WbIv,  unsigned short* __restrict__ WbIc,
    float* __restrict__ S)
{
    const int tid = blockIdx.x * 256 + threadIdx.x;
    for (int i = tid; i < 9 * 128 * 32; i += gridDim.x * 256) {
        int s = i >> 12, rem = i & 4095, c = rem >> 5, k = rem & 31;
        int src = (s * 32 + k) * 128 + c;
        WbVar[i] = f2bf(Wvar[src]);
        WbCon[i] = f2bf(Wcon[src]);
    }
    for (int i = tid; i < 128 * 32; i += gridDim.x * 256) {
        int c = i >> 5, k = i & 31;
        int src = k * 128 + c;
        WbIv[i] = f2bf(Wiv[src]);
        WbIc[i] = f2bf(Wic[src]);
    }
    if (tid == 0) S[0] = 0.f;
}

// ---------------------------------------------------------------- x -> bf16 (8 elems/thread)
__global__ __launch_bounds__(256) void xpack_kernel(
    const float* __restrict__ x, unsigned short* __restrict__ xb, int n8)
{
    int i = blockIdx.x * 256 + threadIdx.x;
    if (i >= n8) return;
    const float4* p = (const float4*)(x + (size_t)i * 8);
    float4 a = p[0], b = p[1];
    uint4 o;
    o.x = (unsigned)f2bf(a.x) | ((unsigned)f2bf(a.y) << 16);
    o.y = (unsigned)f2bf(a.z) | ((unsigned)f2bf(a.w) << 16);
    o.z = (unsigned)f2bf(b.x) | ((unsigned)f2bf(b.y) << 16);
    o.w = (unsigned)f2bf(b.z) | ((unsigned)f2bf(b.w) << 16);
    *(uint4*)(xb + (size_t)i * 8) = o;
}

// ---------------------------------------------------------------- init: h = bf16(x) @ W + b
__global__ __launch_bounds__(256) void init_mfma(
    const float* __restrict__ x,          // M x 32 (pre-offset)
    const unsigned short* __restrict__ Wb,
    const float* __restrict__ bias,
    unsigned short* __restrict__ hout, int M)
{
    const int t = threadIdx.x;
    const int lane = t & 63;
    const int w = t >> 6;
    const int lrow = lane & 15;
    const int lg = lane >> 4;
    const int wrow0 = blockIdx.x * 64 + w * 16;
    int arow = wrow0 + lrow;
    int arowc = arow < M ? arow : M - 1;

    const float4* xp = (const float4*)(x + (size_t)arowc * 32 + lg * 8);
    float4 xa = xp[0], xb = xp[1];
    short8 afr;
    afr[0] = (short)f2bf(xa.x); afr[1] = (short)f2bf(xa.y);
    afr[2] = (short)f2bf(xa.z); afr[3] = (short)f2bf(xa.w);
    afr[4] = (short)f2bf(xb.x); afr[5] = (short)f2bf(xb.y);
    afr[6] = (short)f2bf(xb.z); afr[7] = (short)f2bf(xb.w);

    #pragma unroll
    for (int ct = 0; ct < 8; ++ct) {
        int c = ct * 16 + lrow;
        short8 bfr = *(const short8*)(Wb + (size_t)c * 32 + lg * 8);
        f32x4 acc = {0.f, 0.f, 0.f, 0.f};
        acc = __builtin_amdgcn_mfma_f32_16x16x32_bf16(afr, bfr, acc, 0, 0, 0);
        float bv = bias[c];
        #pragma unroll
        for (int r = 0; r < 4; ++r) {
            int orow = wrow0 + lg * 4 + r;
            if (orow < M) hout[(size_t)orow * 128 + c] = f2bf(acc[r] + bv);
        }
    }
}

// ---------------------------------------------------------------- gather-sum (bf16, coalesced)
template<int DEG>
__global__ __launch_bounds__(256) void agg_bf16(
    const unsigned short* __restrict__ hnb, const int* __restrict__ idx,
    unsigned short* __restrict__ agg, int M)
{
    const int tid = blockIdx.x * 256 + threadIdx.x;
    const int row = tid >> 4;
    const int part = tid & 15;
    if (row >= M) return;
    int nb[DEG];
    #pragma unroll
    for (int d4 = 0; d4 < DEG / 4; ++d4)
        *(int4*)(&nb[d4 * 4]) = *(const int4*)(idx + (size_t)row * DEG + d4 * 4);
    float a0=0.f,a1=0.f,a2=0.f,a3=0.f,a4=0.f,a5=0.f,a6=0.f,a7=0.f;
    #pragma unroll
    for (int b = 0; b < DEG; b += 8) {
        uint4 q[8];
        #pragma unroll
        for (int j = 0; j < 8; ++j)
            q[j] = *(const uint4*)(hnb + (size_t)nb[b + j] * 128 + part * 8);
        #pragma unroll
        for (int j = 0; j < 8; ++j) {
            a0 += bflo(q[j].x); a1 += bfhi(q[j].x);
            a2 += bflo(q[j].y); a3 += bfhi(q[j].y);
            a4 += bflo(q[j].z); a5 += bfhi(q[j].z);
            a6 += bflo(q[j].w); a7 += bfhi(q[j].w);
        }
    }
    uint4 o;
    o.x = (unsigned)f2bf(a0) | ((unsigned)f2bf(a1) << 16);
    o.y = (unsigned)f2bf(a2) | ((unsigned)f2bf(a3) << 16);
    o.z = (unsigned)f2bf(a4) | ((unsigned)f2bf(a5) << 16);
    o.w = (unsigned)f2bf(a6) | ((unsigned)f2bf(a7) << 16);
    *(uint4*)(agg + (size_t)row * 128 + part * 8) = o;
}

// ---------------------------------------------------------------- pipelined persistent MFMA layer:
// h_out = [agg | h_self | x_self] @ W + b  (K = 288 = 9 steps)
// Grid-stride over 64-row tiles; stage(t+1) async BEFORE compute(t); one barrier per tile.
// FINAL: emit dot1[row] = h·Wq[128:] per row; accumulate S += Σ h·Wq[:128] (one atomic/block).
template<bool FINAL>
__global__ __launch_bounds__(256, 2) void gemm_mfma(
    const unsigned short* hself,      // may alias hout (in-place v-update; tiles are owner-private)
    const unsigned short* __restrict__ aggin,
    const unsigned short* __restrict__ xbself,   // M x 32 bf16 (pre-packed)
    const unsigned short* __restrict__ Wb,
    const float* __restrict__ bias,
    unsigned short* hout,
    const float* __restrict__ Wq, float* __restrict__ S, float* __restrict__ dotout,
    int M)
{
    __shared__ __align__(16) unsigned short A0a[64 * 128], A0s[64 * 128];
    __shared__ __align__(16) unsigned short A1a[64 * 128], A1s[64 * 128];
    __shared__ __align__(16) unsigned short X0[64 * 32],  X1[64 * 32];
    __shared__ float red[4];
    const int t = threadIdx.x;
    const int lane = t & 63;
    const int w = t >> 6;
    const int lrow = lane & 15;
    const int lg = lane >> 4;
    const int ntiles = (M + 63) >> 6;

    float Sacc = 0.f;

    auto stage = [&](unsigned short* La, unsigned short* Ls, unsigned short* Lx, int tile) {
        const int r0 = tile * 64;
        #pragma unroll
        for (int i = 0; i < 4; ++i) {
            int L = i * 256 + t;
            int row = L >> 4, c = L & 15;
            int gr = r0 + row;
            int grc = gr < M ? gr : M - 1;
            int cs = c ^ (row & 7);    // inverse swizzle on SOURCE; LDS dest linear
            __builtin_amdgcn_global_load_lds((as1cv)(aggin + (size_t)grc * 128 + cs * 8),
                                             (as3v)(La + (size_t)L * 8), 16, 0, 0);
            __builtin_amdgcn_global_load_lds((as1cv)(hself + (size_t)grc * 128 + cs * 8),
                                             (as3v)(Ls + (size_t)L * 8), 16, 0, 0);
        }
        {   // x tile: 64 rows x 32 bf16 = 256 x 16B chunks
            int row = t >> 2, c = t & 3;
            int gr = r0 + row;
            int grc = gr < M ? gr : M - 1;
            int cs = c ^ (row & 3);
            __builtin_amdgcn_global_load_lds((as1cv)(xbself + (size_t)grc * 32 + cs * 8),
                                             (as3v)(Lx + (size_t)t * 8), 16, 0, 0);
        }
    };

    auto compute = [&](const unsigned short* La, const unsigned short* Ls,
                       const unsigned short* Lx, int tile) {
        const int wrow0 = tile * 64 + w * 16;
        auto dsA = [&](const unsigned short* base, int srel) -> short8 {
            int chunk = (4 * srel + lg) ^ (lrow & 7);
            return *(const short8*)(base + ((size_t)(w * 16 + lrow) * 16 + chunk) * 8);
        };
        short8 bA[8], bB[8];
        #pragma unroll
        for (int ct = 0; ct < 8; ++ct)
            bA[ct] = *(const short8*)(Wb + (size_t)(ct * 16 + lrow) * 32 + lg * 8);
        short8 afr = dsA(La, 0);
        f32x4 acc[8];
        #pragma unroll
        for (int ct = 0; ct < 8; ++ct) acc[ct] = (f32x4){0.f, 0.f, 0.f, 0.f};

        #pragma unroll
        for (int s = 0; s < 9; ++s) {
            short8 anext;
            if (s < 8) {
                short8* bn = (s & 1) ? bA : bB;
                #pragma unroll
                for (int ct = 0; ct < 8; ++ct)
                    bn[ct] = *(const short8*)(
                        Wb + ((size_t)(s + 1) * 128 + ct * 16 + lrow) * 32 + lg * 8);
                if (s + 1 < 4)      anext = dsA(La, s + 1);
                else if (s + 1 < 8) anext = dsA(Ls, s + 1 - 4);
                else {
                    int chunk = lg ^ (lrow & 3);
                    anext = *(const short8*)(Lx + ((size_t)(w * 16 + lrow) * 4 + chunk) * 8);
                }
            }
            const short8* bc = (s & 1) ? bB : bA;
            #pragma unroll
            for (int ct = 0; ct < 8; ++ct)
                acc[ct] = __builtin_amdgcn_mfma_f32_16x16x32_bf16(afr, bc[ct], acc[ct], 0, 0, 0);
            afr = anext;
        }

        if (!FINAL) {
            #pragma unroll
            for (int ct = 0; ct < 8; ++ct) {
                int c = ct * 16 + lrow;
                float bv = bias[c];
                #pragma unroll
                for (int r = 0; r < 4; ++r) {
                    int orow = wrow0 + lg * 4 + r;
                    if (orow < M) hout[(size_t)orow * 128 + c] = f2bf(acc[ct][r] + bv);
                }
            }
        } else {
            float d0[4] = {0.f, 0.f, 0.f, 0.f};
            float d1[4] = {0.f, 0.f, 0.f, 0.f};
            #pragma unroll
            for (int ct = 0; ct < 8; ++ct) {
                int c = ct * 16 + lrow;
                float bv = bias[c];
                float wq0 = Wq[c];
                float wq1 = Wq[128 + c];
                #pragma unroll
                for (int r = 0; r < 4; ++r) {
                    int orow = wrow0 + lg * 4 + r;
                    float val = (orow < M) ? (acc[ct][r] + bv) : 0.f;
                    d0[r] += val * wq0;
                    d1[r] += val * wq1;
                }
            }
            #pragma unroll
            for (int r = 0; r < 4; ++r) {
                d0[r] += __shfl_xor(d0[r], 1); d0[r] += __shfl_xor(d0[r], 2);
                d0[r] += __shfl_xor(d0[r], 4); d0[r] += __shfl_xor(d0[r], 8);
                d1[r] += __shfl_xor(d1[r], 1); d1[r] += __shfl_xor(d1[r], 2);
                d1[r] += __shfl_xor(d1[r], 4); d1[r] += __shfl_xor(d1[r], 8);
            }
            if (lrow == 0) {
                #pragma unroll
                for (int r = 0; r < 4; ++r) {
                    int orow = wrow0 + lg * 4 + r;
                    if (orow < M) dotout[orow] = d1[r];
                }
            }
            float tot = d0[0] + d0[1] + d0[2] + d0[3];
            tot += __shfl_xor(tot, 16);
            tot += __shfl_xor(tot, 32);
            Sacc += tot;
        }
    };

    int tile = blockIdx.x;
    if (tile < ntiles) {
        stage(A0a, A0s, X0, tile);
        __syncthreads();                       // prologue drain
        while (true) {
            int nxt = tile + gridDim.x;
            if (nxt < ntiles) stage(A1a, A1s, X1, nxt);   // issue BEFORE compute
            compute(A0a, A0s, X0, tile);
            __syncthreads();                   // drain stage(nxt) after compute overlap
            if (nxt >= ntiles) break;
            tile = nxt;
            nxt = tile + gridDim.x;
            if (nxt < ntiles) stage(A0a, A0s, X0, nxt);
            compute(A1a, A1s, X1, tile);
            __syncthreads();
            if (nxt >= ntiles) break;
            tile = nxt;
        }
    }
    if (FINAL) {
        if (lane == 0) red[w] = Sacc;
        __syncthreads();
        if (t == 0) atomicAdd(S, red[0] + red[1] + red[2] + red[3]);
    }
}

// ---------------------------------------------------------------- out[i] = dot1[i] + S + bq
__global__ __launch_bounds__(256) void addout_kernel(
    float* __restrict__ outp, const float* __restrict__ S,
    const float* __restrict__ bq, int n)
{
    int i = blockIdx.x * 256 + threadIdx.x;
    if (i < n) outp[i] = outp[i] + S[0] + bq[0];
}

extern "C" void kernel_launch(void* const* d_in, const int* in_sizes, int n_in,
                              void* d_out, int out_size, void* d_ws, size_t ws_size,
                              hipStream_t stream)
{
    const float* x    = (const float*)d_in[0];
    const int*   vci  = (const int*)  d_in[1];   // NV x 8,  values < NC
    const int*   cvi  = (const int*)  d_in[2];   // NC x 16, values < NV
    const float* Wiv  = (const float*)d_in[3];
    const float* biv  = (const float*)d_in[4];
    const float* Wic  = (const float*)d_in[5];
    const float* bic  = (const float*)d_in[6];
    const float* Wvar = (const float*)d_in[7];
    const float* bvar = (const float*)d_in[8];
    const float* Wcon = (const float*)d_in[9];
    const float* bcon = (const float*)d_in[10];
    const float* Wq   = (const float*)d_in[11];
    const float* bq   = (const float*)d_in[12];
    float* outp = (float*)d_out;

    unsigned short* us = (unsigned short*)d_ws;
    size_t o = 0;
    unsigned short* vA    = us + o; o += (size_t)NV * 128;   // v0, then v1 in-place
    unsigned short* cA    = us + o; o += (size_t)NC * 128;   // c0
    unsigned short* cB    = us + o; o += (size_t)NC * 128;   // c1
    unsigned short* aggV  = us + o; o += (size_t)NV * 128;   // agg for v-layers
    unsigned short* aggC  = us + o; o += (size_t)NC * 128;   // agg for c-layer
    unsigned short* xbV   = us + o; o += (size_t)NV * 32;    // bf16 x (var rows)
    unsigned short* xbC   = us + o; o += (size_t)NC * 32;    // bf16 x (con rows)
    unsigned short* WbVar = us + o; o += 9 * 128 * 32;
    unsigned short* WbCon = us + o; o += 9 * 128 * 32;
    unsigned short* WbIv  = us + o; o += 128 * 32;
    unsigned short* WbIc  = us + o; o += 128 * 32;
    float* S = (float*)(us + o);

    const float* xc = x + (size_t)NV * 32;

    // weight pack + S zero; x -> bf16
    pack_kernel<<<144, 256, 0, stream>>>(Wvar, Wcon, Wiv, Wic, WbVar, WbCon, WbIv, WbIc, S);
    xpack_kernel<<<((NV + NC) * 4 + 255) / 256, 256, 0, stream>>>(x, xbV, (NV + NC) * 4);
    // init
    init_mfma<<<(NV + 63) / 64, 256, 0, stream>>>(x,  WbIv, biv, vA, NV);
    init_mfma<<<(NC + 63) / 64, 256, 0, stream>>>(xc, WbIc, bic, cA, NC);

    // layer 1 aggregations
    agg_bf16<DCON><<<(NC * 16 + 255) / 256, 256, 0, stream>>>(vA, cvi, aggC, NC);
    agg_bf16<DVAR><<<(NV * 16 + 255) / 256, 256, 0, stream>>>(cA, vci, aggV, NV);
    // c1 = f(aggC, c0, xc)
    gemm_mfma<false><<<512, 256, 0, stream>>>(
        cA, aggC, xbC, WbCon, bcon, cB, nullptr, nullptr, nullptr, NC);
    // v1 = f(aggV, v0, xv)  [in-place: tiles are owner-private]
    gemm_mfma<false><<<512, 256, 0, stream>>>(
        vA, aggV, xbV, WbVar, bvar, vA, nullptr, nullptr, nullptr, NV);

    // layer 2: agg over c1, then v2-GEMM fused with readout (c2 dead)
    agg_bf16<DVAR><<<(NV * 16 + 255) / 256, 256, 0, stream>>>(cB, vci, aggV, NV);
    gemm_mfma<true><<<512, 256, 0, stream>>>(
        vA, aggV, xbV, WbVar, bvar, nullptr, Wq, S, outp, NV);

    // out[i] = dot1[i] + (g·Wq[:128]) + bq
    addout_kernel<<<(NV + 255) / 256, 256, 0, stream>>>(outp, S, bq, NV);
}

// Round 12
// 267.546 us; speedup vs baseline: 1.7814x; 1.7814x over previous
//
#include <hip/hip_runtime.h>

#define NV 100000
#define NC 50000
#define DVAR 8
#define DCON 16

using short8 = __attribute__((ext_vector_type(8))) short;
using f32x4  = __attribute__((ext_vector_type(4))) float;

typedef const __attribute__((address_space(1))) void* as1cv;
typedef __attribute__((address_space(3))) void* as3v;

__device__ __forceinline__ unsigned short f2bf(float f) {
    union { float f; unsigned int u; } v; v.f = f;
    return (unsigned short)((v.u + 0x7fffu + ((v.u >> 16) & 1u)) >> 16);  // RNE
}
__device__ __forceinline__ float bflo(unsigned int u) {
    union { unsigned int u; float f; } v; v.u = u << 16; return v.f;
}
__device__ __forceinline__ float bfhi(unsigned int u) {
    union { unsigned int u; float f; } v; v.u = u & 0xffff0000u; return v.f;
}

// ---------------------------------------------------------------- pack W into MFMA B-fragment
__global__ __launch_bounds__(256) void pack_kernel(
    const float* __restrict__ Wvar, const float* __restrict__ Wcon,
    const float* __restrict__ Wiv,  const float* __restrict__ Wic,
    unsigned short* __restrict__ WbVar, unsigned short* __restrict__ WbCon,
    unsigned short* __restrict__ WbIv,  unsigned short* __restrict__ WbIc,
    float* __restrict__ S)
{
    const int tid = blockIdx.x * 256 + threadIdx.x;
    for (int i = tid; i < 9 * 128 * 32; i += gridDim.x * 256) {
        int s = i >> 12, rem = i & 4095, c = rem >> 5, k = rem & 31;
        int src = (s * 32 + k) * 128 + c;
        WbVar[i] = f2bf(Wvar[src]);
        WbCon[i] = f2bf(Wcon[src]);
    }
    for (int i = tid; i < 128 * 32; i += gridDim.x * 256) {
        int c = i >> 5, k = i & 31;
        int src = k * 128 + c;
        WbIv[i] = f2bf(Wiv[src]);
        WbIc[i] = f2bf(Wic[src]);
    }
    if (tid == 0) S[0] = 0.f;
}

// ---------------------------------------------------------------- x -> bf16 (8 elems/thread)
__global__ __launch_bounds__(256) void xpack_kernel(
    const float* __restrict__ x, unsigned short* __restrict__ xb, int n8)
{
    int i = blockIdx.x * 256 + threadIdx.x;
    if (i >= n8) return;
    const float4* p = (const float4*)(x + (size_t)i * 8);
    float4 a = p[0], b = p[1];
    uint4 o;
    o.x = (unsigned)f2bf(a.x) | ((unsigned)f2bf(a.y) << 16);
    o.y = (unsigned)f2bf(a.z) | ((unsigned)f2bf(a.w) << 16);
    o.z = (unsigned)f2bf(b.x) | ((unsigned)f2bf(b.y) << 16);
    o.w = (unsigned)f2bf(b.z) | ((unsigned)f2bf(b.w) << 16);
    *(uint4*)(xb + (size_t)i * 8) = o;
}

// ---------------------------------------------------------------- init: h = bf16(x) @ W + b
__global__ __launch_bounds__(256) void init_mfma(
    const float* __restrict__ x,          // M x 32 (pre-offset)
    const unsigned short* __restrict__ Wb,
    const float* __restrict__ bias,
    unsigned short* __restrict__ hout, int M)
{
    const int t = threadIdx.x;
    const int lane = t & 63;
    const int w = t >> 6;
    const int lrow = lane & 15;
    const int lg = lane >> 4;
    const int wrow0 = blockIdx.x * 64 + w * 16;
    int arow = wrow0 + lrow;
    int arowc = arow < M ? arow : M - 1;

    const float4* xp = (const float4*)(x + (size_t)arowc * 32 + lg * 8);
    float4 xa = xp[0], xb = xp[1];
    short8 afr;
    afr[0] = (short)f2bf(xa.x); afr[1] = (short)f2bf(xa.y);
    afr[2] = (short)f2bf(xa.z); afr[3] = (short)f2bf(xa.w);
    afr[4] = (short)f2bf(xb.x); afr[5] = (short)f2bf(xb.y);
    afr[6] = (short)f2bf(xb.z); afr[7] = (short)f2bf(xb.w);

    #pragma unroll
    for (int ct = 0; ct < 8; ++ct) {
        int c = ct * 16 + lrow;
        short8 bfr = *(const short8*)(Wb + (size_t)c * 32 + lg * 8);
        f32x4 acc = {0.f, 0.f, 0.f, 0.f};
        acc = __builtin_amdgcn_mfma_f32_16x16x32_bf16(afr, bfr, acc, 0, 0, 0);
        float bv = bias[c];
        #pragma unroll
        for (int r = 0; r < 4; ++r) {
            int orow = wrow0 + lg * 4 + r;
            if (orow < M) hout[(size_t)orow * 128 + c] = f2bf(acc[r] + bv);
        }
    }
}

// ---------------------------------------------------------------- fused layer (B-in-LDS, deep gather):
// h_out = [agg(h_nb[idx]) | h_self | x_self] @ W + b   (K = 288 = 9 steps)
// Phase 0 (async): Wb steps 0..7 -> LDS (64 KB).  Phase 1: deep-batched gather -> swizzled LDS tile.
// Phase 2 (after ONE barrier): MFMA; B via ds_read, A-agg via swizzled ds_read; self/x/B8 global.
// FINAL: dot1[row] = h·Wq[128:], S += sum h·Wq[:128].
template<int DEG, bool FINAL>
__global__ __launch_bounds__(256, 2) void layer_fused(
    const unsigned short* hself,      // may alias hout (in-place; blocks own their 64 rows)
    const unsigned short* __restrict__ hnb,
    const unsigned short* __restrict__ xb,    // M x 32 bf16
    const int* __restrict__ idx,
    const unsigned short* __restrict__ Wb,    // 9*128*32 bf16 fragments
    const float* __restrict__ bias,
    unsigned short* hout,
    const float* __restrict__ Wq, float* __restrict__ S, float* __restrict__ dotout,
    int M)
{
    __shared__ __align__(16) unsigned short Bs[8 * 128 * 32];  // 65536 B
    __shared__ __align__(16) unsigned short As[64 * 128];      // 16384 B (swizzled 16B chunks)
    const int t = threadIdx.x;
    const int lane = t & 63;
    const int w = t >> 6;
    const int lrow = lane & 15;
    const int lg = lane >> 4;
    const int r0 = blockIdx.x * 64;

    // ---- phase 0: stage B (s=0..7) into LDS, async; drained by the barrier below
    #pragma unroll
    for (int i = 0; i < 16; ++i) {
        int chunk = i * 256 + t;           // 4096 x 16B
        __builtin_amdgcn_global_load_lds((as1cv)(Wb + (size_t)chunk * 8),
                                         (as3v)(Bs + (size_t)chunk * 8), 16, 0, 0);
    }

    // ---- phase 1: gather. Each thread owns 4 (row,slice) pairs; 32 loads per batch in flight.
    {
        const int slice = t & 15;          // 16B slice within row
        const int rbase = t >> 4;          // 0..15
        float ac[4][8];
        #pragma unroll
        for (int p = 0; p < 4; ++p)
            #pragma unroll
            for (int j = 0; j < 8; ++j) ac[p][j] = 0.f;

        #pragma unroll
        for (int h = 0; h < DEG; h += 8) {
            int nb8[4][8];
            #pragma unroll
            for (int p = 0; p < 4; ++p) {
                int row = r0 + p * 16 + rbase;
                int rowc = row < M ? row : M - 1;
                *(int4*)&nb8[p][0] = *(const int4*)(idx + (size_t)rowc * DEG + h);
                *(int4*)&nb8[p][4] = *(const int4*)(idx + (size_t)rowc * DEG + h + 4);
            }
            uint4 q[4][8];
            #pragma unroll
            for (int p = 0; p < 4; ++p)
                #pragma unroll
                for (int j = 0; j < 8; ++j)
                    q[p][j] = *(const uint4*)(hnb + (size_t)nb8[p][j] * 128 + slice * 8);
            #pragma unroll
            for (int p = 0; p < 4; ++p)
                #pragma unroll
                for (int j = 0; j < 8; ++j) {
                    ac[p][0] += bflo(q[p][j].x); ac[p][1] += bfhi(q[p][j].x);
                    ac[p][2] += bflo(q[p][j].y); ac[p][3] += bfhi(q[p][j].y);
                    ac[p][4] += bflo(q[p][j].z); ac[p][5] += bfhi(q[p][j].z);
                    ac[p][6] += bflo(q[p][j].w); ac[p][7] += bfhi(q[p][j].w);
                }
        }
        #pragma unroll
        for (int p = 0; p < 4; ++p) {
            int rl = p * 16 + rbase;
            int cs = slice ^ (rl & 7);     // swizzle chunks within 8-row stripes
            uint4 o;
            o.x = (unsigned)f2bf(ac[p][0]) | ((unsigned)f2bf(ac[p][1]) << 16);
            o.y = (unsigned)f2bf(ac[p][2]) | ((unsigned)f2bf(ac[p][3]) << 16);
            o.z = (unsigned)f2bf(ac[p][4]) | ((unsigned)f2bf(ac[p][5]) << 16);
            o.w = (unsigned)f2bf(ac[p][6]) | ((unsigned)f2bf(ac[p][7]) << 16);
            *(uint4*)(As + ((size_t)rl * 16 + cs) * 8) = o;
        }
    }
    __syncthreads();   // drains B staging (vmcnt) and gather LDS writes (lgkmcnt)

    // ---- phase 2: MFMA
    const int wrow0 = r0 + w * 16;
    const int arow = wrow0 + lrow;
    const int arowc = arow < M ? arow : M - 1;

    // early independent global loads: self rows, x row, B step-8 fragments
    short8 sfr[4];
    #pragma unroll
    for (int s4 = 0; s4 < 4; ++s4)
        sfr[s4] = *(const short8*)(hself + (size_t)arowc * 128 + s4 * 32 + lg * 8);
    short8 xfr = *(const short8*)(xb + (size_t)arowc * 32 + lg * 8);
    short8 b8[8];
    #pragma unroll
    for (int ct = 0; ct < 8; ++ct)
        b8[ct] = *(const short8*)(Wb + ((size_t)8 * 128 + ct * 16 + lrow) * 32 + lg * 8);

    f32x4 acc[8];
    #pragma unroll
    for (int ct = 0; ct < 8; ++ct) acc[ct] = (f32x4){0.f, 0.f, 0.f, 0.f};

    #pragma unroll
    for (int s = 0; s < 8; ++s) {
        short8 afr;
        if (s < 4) {
            int chunk = (4 * s + lg) ^ (lrow & 7);
            afr = *(const short8*)(As + ((size_t)(w * 16 + lrow) * 16 + chunk) * 8);
        } else {
            afr = sfr[s - 4];
        }
        #pragma unroll
        for (int ct = 0; ct < 8; ++ct) {
            short8 bfr = *(const short8*)(Bs + ((size_t)s * 128 + ct * 16 + lrow) * 32 + lg * 8);
            acc[ct] = __builtin_amdgcn_mfma_f32_16x16x32_bf16(afr, bfr, acc[ct], 0, 0, 0);
        }
    }
    #pragma unroll
    for (int ct = 0; ct < 8; ++ct)
        acc[ct] = __builtin_amdgcn_mfma_f32_16x16x32_bf16(xfr, b8[ct], acc[ct], 0, 0, 0);

    // ---- epilogue (C layout: col = ct*16 + lrow, row = wrow0 + lg*4 + reg)
    if (!FINAL) {
        #pragma unroll
        for (int ct = 0; ct < 8; ++ct) {
            int c = ct * 16 + lrow;
            float bv = bias[c];
            #pragma unroll
            for (int r = 0; r < 4; ++r) {
                int orow = wrow0 + lg * 4 + r;
                if (orow < M) hout[(size_t)orow * 128 + c] = f2bf(acc[ct][r] + bv);
            }
        }
    } else {
        float d0[4] = {0.f, 0.f, 0.f, 0.f};
        float d1[4] = {0.f, 0.f, 0.f, 0.f};
        #pragma unroll
        for (int ct = 0; ct < 8; ++ct) {
            int c = ct * 16 + lrow;
            float bv = bias[c];
            float wq0 = Wq[c];
            float wq1 = Wq[128 + c];
            #pragma unroll
            for (int r = 0; r < 4; ++r) {
                int orow = wrow0 + lg * 4 + r;
                float val = (orow < M) ? (acc[ct][r] + bv) : 0.f;
                d0[r] += val * wq0;
                d1[r] += val * wq1;
            }
        }
        #pragma unroll
        for (int r = 0; r < 4; ++r) {
            d0[r] += __shfl_xor(d0[r], 1); d0[r] += __shfl_xor(d0[r], 2);
            d0[r] += __shfl_xor(d0[r], 4); d0[r] += __shfl_xor(d0[r], 8);
            d1[r] += __shfl_xor(d1[r], 1); d1[r] += __shfl_xor(d1[r], 2);
            d1[r] += __shfl_xor(d1[r], 4); d1[r] += __shfl_xor(d1[r], 8);
        }
        if (lrow == 0) {
            #pragma unroll
            for (int r = 0; r < 4; ++r) {
                int orow = wrow0 + lg * 4 + r;
                if (orow < M) dotout[orow] = d1[r];
            }
        }
        float tot = d0[0] + d0[1] + d0[2] + d0[3];
        tot += __shfl_xor(tot, 16);
        tot += __shfl_xor(tot, 32);
        __syncthreads();                      // all As reads done; reuse As as reduction scratch
        float* red = (float*)As;
        if (lane == 0) red[w] = tot;
        __syncthreads();
        if (t == 0) atomicAdd(S, red[0] + red[1] + red[2] + red[3]);
    }
}

// ---------------------------------------------------------------- out[i] = dot1[i] + S + bq
__global__ __launch_bounds__(256) void addout_kernel(
    float* __restrict__ outp, const float* __restrict__ S,
    const float* __restrict__ bq, int n)
{
    int i = blockIdx.x * 256 + threadIdx.x;
    if (i < n) outp[i] = outp[i] + S[0] + bq[0];
}

extern "C" void kernel_launch(void* const* d_in, const int* in_sizes, int n_in,
                              void* d_out, int out_size, void* d_ws, size_t ws_size,
                              hipStream_t stream)
{
    const float* x    = (const float*)d_in[0];
    const int*   vci  = (const int*)  d_in[1];   // NV x 8,  values < NC
    const int*   cvi  = (const int*)  d_in[2];   // NC x 16, values < NV
    const float* Wiv  = (const float*)d_in[3];
    const float* biv  = (const float*)d_in[4];
    const float* Wic  = (const float*)d_in[5];
    const float* bic  = (const float*)d_in[6];
    const float* Wvar = (const float*)d_in[7];
    const float* bvar = (const float*)d_in[8];
    const float* Wcon = (const float*)d_in[9];
    const float* bcon = (const float*)d_in[10];
    const float* Wq   = (const float*)d_in[11];
    const float* bq   = (const float*)d_in[12];
    float* outp = (float*)d_out;

    unsigned short* us = (unsigned short*)d_ws;
    size_t o = 0;
    unsigned short* vA    = us + o; o += (size_t)NV * 128;        // v0, then v1 in-place
    unsigned short* cA    = us + o; o += (size_t)NC * 128;        // c0
    unsigned short* cB    = us + o; o += (size_t)NC * 128;        // c1
    unsigned short* xbAll = us + o; o += (size_t)(NV + NC) * 32;  // bf16 x
    unsigned short* WbVar = us + o; o += 9 * 128 * 32;
    unsigned short* WbCon = us + o; o += 9 * 128 * 32;
    unsigned short* WbIv  = us + o; o += 128 * 32;
    unsigned short* WbIc  = us + o; o += 128 * 32;
    float* S = (float*)(us + o);

    const float* xc = x + (size_t)NV * 32;
    unsigned short* xbV = xbAll;
    unsigned short* xbC = xbAll + (size_t)NV * 32;

    // weight pack + S zero; x -> bf16
    pack_kernel<<<144, 256, 0, stream>>>(Wvar, Wcon, Wiv, Wic, WbVar, WbCon, WbIv, WbIc, S);
    xpack_kernel<<<((NV + NC) * 4 + 255) / 256, 256, 0, stream>>>(x, xbAll, (NV + NC) * 4);
    // init
    init_mfma<<<(NV + 63) / 64, 256, 0, stream>>>(x,  WbIv, biv, vA, NV);
    init_mfma<<<(NC + 63) / 64, 256, 0, stream>>>(xc, WbIc, bic, cA, NC);

    // layer 1: c1 = f(agg(v0), c0, xc)   [reads vA via gather; must precede v-update]
    layer_fused<DCON, false><<<(NC + 63) / 64, 256, 0, stream>>>(
        cA, vA, xbC, cvi, WbCon, bcon, cB, nullptr, nullptr, nullptr, NC);
    //          v1 = f(agg(c0), v0, xv)   [in-place]
    layer_fused<DVAR, false><<<(NV + 63) / 64, 256, 0, stream>>>(
        vA, cA, xbV, vci, WbVar, bvar, vA, nullptr, nullptr, nullptr, NV);
    // layer 2: v2 = f(agg(c1), v1, xv) fused with readout (c2 dead)
    layer_fused<DVAR, true><<<(NV + 63) / 64, 256, 0, stream>>>(
        vA, cB, xbV, vci, WbVar, bvar, nullptr, Wq, S, outp, NV);

    // out[i] = dot1[i] + (g·Wq[:128]) + bq
    addout_kernel<<<(NV + 255) / 256, 256, 0, stream>>>(outp, S, bq, NV);
}